// Round 11
// baseline (500.196 us; speedup 1.0000x reference)
//
#include <hip/hip_runtime.h>
#include <hip/hip_fp16.h>

#define N_NODES 100000
#define N_EDGES 1600000
#define DIM 128
#define NC 40

#define BUCKET_SHIFT 7
#define BUCKET_NODES 128
#define NBUCKET ((N_NODES + BUCKET_NODES - 1) / BUCKET_NODES)   // 782
#define SEGCAP 3072                                             // mean bucket load 2048, sigma 45
#define NBIN 1024                                               // padded bins for LDS scan
#define EPB 4096                                                // edges per binfill block
#define NBLK_FILL ((N_EDGES + EPB - 1) / EPB)                   // 391

#define NBLK_CVT (N_NODES * DIM / 8 / 256)                      // 6250
#define NBLK_PACK 20                                            // 16 W1a/W1b + 3 Pc + 1 Wq

typedef _Float16 f16x8 __attribute__((ext_vector_type(8)));
typedef float f32x4 __attribute__((ext_vector_type(4)));

// add 8 halves (as uint4) into acc[0..8)
__device__ __forceinline__ void acc_row8(float* acc, uint4 v) {
    __half2 h;
    float2 f;
    *(unsigned*)&h = v.x; f = __half22float2(h); acc[0] += f.x; acc[1] += f.y;
    *(unsigned*)&h = v.y; f = __half22float2(h); acc[2] += f.x; acc[3] += f.y;
    *(unsigned*)&h = v.z; f = __half22float2(h); acc[4] += f.x; acc[5] += f.y;
    *(unsigned*)&h = v.w; f = __half22float2(h); acc[6] += f.x; acc[7] += f.y;
}

// ---------------- binfill: LDS counting-sort edges by 128-node bucket -> fixed-cap segments ----
// staged entry: src | (dst_local << 17)  (src<2^17, dst_local<2^7)
// Block-local LDS atomics + ONE global atomic per non-empty bin per block.
// Launched FIRST (edge chain is the critical path; cvt/pack overlap later in k_mid).
__global__ __launch_bounds__(256) void k_binfill(const int2* __restrict__ ei, int* __restrict__ cnt,
                                                 int* __restrict__ seg) {
    __shared__ int hist[NBIN];
    __shared__ int offs[NBIN];
    __shared__ int gbase[NBIN];
    __shared__ int lcnt[NBIN];
    __shared__ int lds[EPB];
    __shared__ short binof[EPB];   // bin id per staged slot (no phase-5 binary search)
    __shared__ int wt[4];
    int t = threadIdx.x;
    int e0 = blockIdx.x * EPB;
    int bec = N_EDGES - e0; if (bec > EPB) bec = EPB;

    // edge register cache (issued before LDS init; hides latency)
    int2 er[EPB / 256];
    #pragma unroll
    for (int k = 0; k < EPB / 256; ++k) {
        int i = e0 + t + k * 256;
        er[k] = (i < N_EDGES) ? ei[i] : (int2){0, -1};   // y = -1 -> invalid lane
    }

    #pragma unroll
    for (int j = 0; j < NBIN / 256; ++j) { hist[t + j * 256] = 0; lcnt[t + j * 256] = 0; }
    __syncthreads();

    // phase 1: histogram
    #pragma unroll
    for (int k = 0; k < EPB / 256; ++k)
        if (er[k].y >= 0) atomicAdd(&hist[er[k].y >> BUCKET_SHIFT], 1);
    __syncthreads();

    // phase 2: exclusive scan of hist[1024]
    int lane = t & 63, w = t >> 6;
    int h[4], p = 0;
    #pragma unroll
    for (int j = 0; j < 4; ++j) { h[j] = hist[t * 4 + j]; p += h[j]; }
    int inc = p;
    #pragma unroll
    for (int d = 1; d < 64; d <<= 1) {
        int u = __shfl_up(inc, d, 64);
        if (lane >= d) inc += u;
    }
    if (lane == 63) wt[w] = inc;
    __syncthreads();
    int add = inc - p;
    for (int k = 0; k < w; ++k) add += wt[k];
    int run = add;
    #pragma unroll
    for (int j = 0; j < 4; ++j) { offs[t * 4 + j] = run; run += h[j]; }
    __syncthreads();

    // phase 3: reserve segment ranges (one atomic per non-empty bin)
    #pragma unroll
    for (int j = 0; j < 4; ++j) {
        int b = t * 4 + j;
        if (b < NBUCKET && h[j] > 0) gbase[b] = b * SEGCAP + atomicAdd(&cnt[b], h[j]);
    }
    __syncthreads();

    // phase 4: scatter packed edges into LDS in bin order (+ record bin per slot)
    #pragma unroll
    for (int k = 0; k < EPB / 256; ++k) {
        if (er[k].y >= 0) {
            int b = er[k].y >> BUCKET_SHIFT;
            int pos = offs[b] + atomicAdd(&lcnt[b], 1);
            lds[pos] = er[k].x | ((er[k].y & (BUCKET_NODES - 1)) << 17);
            binof[pos] = (short)b;
        }
    }
    __syncthreads();

    // phase 5: coalesced write-out (bin of position i read directly)
    for (int i = t; i < bec; i += 256) {
        int lo = binof[i];
        seg[gbase[lo] + (i - offs[lo])] = lds[i];
    }
}

// ---------------- k_mid: csr_local (782 blocks) || x->fp16 cvt (6250) || weight pack (20) ----------
// csr_local depends on binfill; cvt/pack are independent -> overlapped in one dispatch (saves a
// dispatch AND takes cvt off the critical path). LDS = 1KB (csr_local) so cvt occupancy unharmed.
__global__ __launch_bounds__(256) void k_mid(int* __restrict__ dg, const int* __restrict__ cnt,
                                             const int* __restrict__ seg, int* __restrict__ rs,
                                             int* __restrict__ csr,
                                             const float* __restrict__ x, __half* __restrict__ xh,
                                             __half* __restrict__ y,
                                             const float* __restrict__ W1a, const float* __restrict__ W1b,
                                             const float* __restrict__ W2a, const float* __restrict__ W2b,
                                             _Float16* __restrict__ Pa, _Float16* __restrict__ Pb,
                                             _Float16* __restrict__ Pc, float4* __restrict__ Wq) {
    __shared__ int ldg[BUCKET_NODES];
    __shared__ int cur[BUCKET_NODES];
    __shared__ int wq0;
    int b = blockIdx.x, t = threadIdx.x;

    if (b < NBUCKET) {
        // ---- per-bucket CSR fill: LDS degree hist + local prefix + scatter in 12KB window ----
        int n0 = b * BUCKET_NODES;
        int nn = N_NODES - n0; if (nn > BUCKET_NODES) nn = BUCKET_NODES;
        if (t < BUCKET_NODES) ldg[t] = 0;
        __syncthreads();

        int c = cnt[b];
        // pass 1: per-node degree histogram (LDS atomics)
        for (int i = t; i < c; i += 256)
            atomicAdd(&ldg[(seg[b * SEGCAP + i] >> 17) & (BUCKET_NODES - 1)], 1);
        __syncthreads();

        // local exclusive scan of ldg[0..128) (threads 0..127 over 2 waves)
        int d = (t < BUCKET_NODES) ? ldg[t] : 0;
        int lane = t & 63, w2 = t >> 6;
        int incl = d;
        #pragma unroll
        for (int s = 1; s < 64; s <<= 1) {
            int u = __shfl_up(incl, s, 64);
            if (lane >= s) incl += u;
        }
        if (w2 == 0 && lane == 63) wq0 = incl;
        __syncthreads();
        int excl = incl - d + ((w2 == 1) ? wq0 : 0);
        if (t < nn) {
            int base = b * SEGCAP + excl;
            cur[t] = base;
            rs[n0 + t] = base;
            dg[n0 + t] = d;
        }
        __syncthreads();

        // pass 2: scatter (seg L2-hot from pass 1)
        for (int i = t; i < c; i += 256) {
            int e = seg[b * SEGCAP + i];
            int dl = (e >> 17) & (BUCKET_NODES - 1);
            int pos = atomicAdd(&cur[dl], 1);
            csr[pos] = e & 0x1FFFF;
        }
        return;
    }

    int cb = b - NBUCKET;
    if (cb < NBLK_CVT) {
        // ---- x -> fp16 convert + zero-row init ----
        int i = cb * 256 + t;                        // 6250*256*8 == N_NODES*DIM exactly
        if (cb == 0) {
            if (t < 16) ((uint4*)xh)[(size_t)N_NODES * (DIM / 8) + t] = (uint4){0, 0, 0, 0};
            else if (t < 21) ((uint4*)y)[(size_t)N_NODES * 5 + t - 16] = (uint4){0, 0, 0, 0};
        }
        float4 v0 = ((const float4*)x)[(size_t)i * 2];
        float4 v1 = ((const float4*)x)[(size_t)i * 2 + 1];
        __half2 h01 = __float22half2_rn(make_float2(v0.x, v0.y));
        __half2 h23 = __float22half2_rn(make_float2(v0.z, v0.w));
        __half2 h45 = __float22half2_rn(make_float2(v1.x, v1.y));
        __half2 h67 = __float22half2_rn(make_float2(v1.z, v1.w));
        uint4 o;
        o.x = *(unsigned*)&h01; o.y = *(unsigned*)&h23;
        o.z = *(unsigned*)&h45; o.w = *(unsigned*)&h67;
        ((uint4*)xh)[i] = o;
        return;
    }

    // ---- pack path: W1a/W1b (128x128) and W2a (128x40->48) into fp16 MFMA B-frags; W2b pairs ----
    int bid = cb - NBLK_CVT;
    if (bid < 16) {
        const float* W = (bid < 8) ? W1a : W1b;
        _Float16* P = (bid < 8) ? Pa : Pb;
        int tt = (bid & 7) * 256 + t;           // 0..2047
        int l = tt & 63, nt = (tt >> 6) & 7, kt = tt >> 9;
        int n = nt * 16 + (l & 15);
        int kb = kt * 32 + (l >> 4) * 8;
        #pragma unroll
        for (int j = 0; j < 8; ++j)
            P[(size_t)tt * 8 + j] = (_Float16)W[(size_t)(kb + j) * DIM + n];
    } else if (bid < 19) {
        int tt = (bid - 16) * 256 + t;          // 0..767
        if (tt < 768) {
            int l = tt & 63, u = tt >> 6;        // u = kt*3 + nt
            int nt = u % 3, kt = u / 3;
            int n = nt * 16 + (l & 15);
            int kb = kt * 32 + (l >> 4) * 8;
            #pragma unroll
            for (int j = 0; j < 8; ++j) {
                float wv = (n < NC) ? W2a[(size_t)(kb + j) * NC + n] : 0.f;
                Pc[(size_t)tt * 8 + j] = (_Float16)wv;
            }
        }
    } else {
        // Wq[q*NC + l] = {W2b[4q+0][l], W2b[4q+1][l], W2b[4q+2][l], W2b[4q+3][l]}  (exact f32 copy)
        for (int u = t; u < 10 * NC; u += 256) {
            int q = u / NC, c = u - q * NC;
            float4 wv;
            wv.x = W2b[(4 * q + 0) * NC + c];
            wv.y = W2b[(4 * q + 1) * NC + c];
            wv.z = W2b[(4 * q + 2) * NC + c];
            wv.w = W2b[(4 * q + 3) * NC + c];
            Wq[u] = wv;
        }
    }
}

// ---------------- layer 1 aggregation: hp = x + segsum(x[src]) ----------------
// Four rows per VMEM instruction: 16-lane group g (16 x uint4 = 256 B) loads row s[g].
// Dual-buffer software pipeline: batch k+1's csr+row loads issue before batch k is consumed.
__global__ __launch_bounds__(256) void k_gather1(const __half* __restrict__ xh, const int* __restrict__ rs,
                                                 const int* __restrict__ dg, const int* __restrict__ csr_src,
                                                 __half* __restrict__ hp) {
    int l = threadIdx.x & 63, wid = threadIdx.x >> 6;
    int n = __builtin_amdgcn_readfirstlane(blockIdx.x * 4 + wid);
    int grp = l >> 4, q = l & 15;
    const uint4* x4 = (const uint4*)xh;            // row stride: 16 uint4

    // self row issued early (lanes 0..15; consumed after the loop)
    uint4 sv;
    if (grp == 0) sv = x4[(size_t)n * 16 + q];

    float acc[8] = {0.f, 0.f, 0.f, 0.f, 0.f, 0.f, 0.f, 0.f};
    int i0 = rs[n], e = i0 + dg[n];
    int niter = (e - i0 + 7) >> 3;
    uint4 cur[2];
    if (niter > 0) {
        #pragma unroll
        for (int u = 0; u < 2; ++u) {
            int idx = i0 + u * 4 + grp;
            int s = (idx < e) ? csr_src[idx] : N_NODES;   // N_NODES = zero row (L1-hot)
            cur[u] = x4[(size_t)s * 16 + q];
        }
    }
    for (int k = 1; k < niter; ++k) {
        int base = i0 + k * 8;
        uint4 nxt[2];
        #pragma unroll
        for (int u = 0; u < 2; ++u) {
            int idx = base + u * 4 + grp;
            int s = (idx < e) ? csr_src[idx] : N_NODES;
            nxt[u] = x4[(size_t)s * 16 + q];              // issued before cur is consumed
        }
        acc_row8(acc, cur[0]); cur[0] = nxt[0];
        acc_row8(acc, cur[1]); cur[1] = nxt[1];
    }
    if (niter > 0) {
        acc_row8(acc, cur[0]);
        acc_row8(acc, cur[1]);
    }
    // combine the 4 groups (lanes l, l^16, l^32, l^48 hold the same 8 dims)
    #pragma unroll
    for (int k2 = 0; k2 < 8; ++k2) {
        acc[k2] += __shfl_xor(acc[k2], 16);
        acc[k2] += __shfl_xor(acc[k2], 32);
    }

    if (grp == 0) {
        acc_row8(acc, sv);   // add self row
        __half2 o0 = __float22half2_rn(make_float2(acc[0], acc[1]));
        __half2 o1 = __float22half2_rn(make_float2(acc[2], acc[3]));
        __half2 o2 = __float22half2_rn(make_float2(acc[4], acc[5]));
        __half2 o3 = __float22half2_rn(make_float2(acc[6], acc[7]));
        uint4 ov;
        ov.x = *(unsigned*)&o0; ov.y = *(unsigned*)&o1;
        ov.z = *(unsigned*)&o2; ov.w = *(unsigned*)&o3;
        ((uint4*)hp)[(size_t)n * 16 + q] = ov;
    }
}

// ---------------- fused MLP via fp16 MFMA: y = relu(relu(hp@W1a+b1a)@W1b+b1b) @ W2a ----------------
// Column-split waves: wave w owns col-tiles {2w,2w+1} for ALL 4 row-tiles (GEMM1/2).
// B-frags load ONCE per wave into registers; A-frags re-read from LDS per row-tile.
// GEMM3: 12 tile-tasks round-robined on 4 waves.
__global__ __launch_bounds__(256) void k_mlp(const __half* __restrict__ hp,
    const _Float16* __restrict__ Pa, const _Float16* __restrict__ Pb, const _Float16* __restrict__ Pc,
    const float* __restrict__ b1a, const float* __restrict__ b1b, __half* __restrict__ y) {
    __shared__ _Float16 A[64][136];   // +8 pad (16B): aligned frag reads
    __shared__ _Float16 H[64][136];
    int t = threadIdx.x;
    size_t row0 = (size_t)blockIdx.x * 64;

    for (int i = t; i < 1024; i += 256) {
        int r = i >> 4, c = i & 15;
        size_t g = row0 + r;
        if (g >= N_NODES) g = N_NODES - 1;    // clamped read; stores guarded below
        uint4 v = ((const uint4*)(hp + g * DIM))[c];
        *(uint4*)&A[r][c * 8] = v;
    }
    __syncthreads();

    int w = t >> 6, l = t & 63;
    int lrow = l & 15;                 // A-frag row within tile
    int kq = (l >> 4) * 8;
    int csub = (l >> 4) * 4;           // C-layout row sub-base
    int ccol = l & 15;
    int nt0 = 2 * w, nt1 = 2 * w + 1;

    // ---- GEMM1: A @ W1a + b1a, relu -> H  (wave w: cols [32w, 32w+32)) ----
    {
        f16x8 bf0[4], bf1[4];
        #pragma unroll
        for (int kt = 0; kt < 4; ++kt) {
            bf0[kt] = *(const f16x8*)(Pa + ((size_t)((kt << 3) + nt0) * 64 + l) * 8);
            bf1[kt] = *(const f16x8*)(Pa + ((size_t)((kt << 3) + nt1) * 64 + l) * 8);
        }
        float b0 = b1a[nt0 * 16 + ccol], b1 = b1a[nt1 * 16 + ccol];
        #pragma unroll
        for (int rt = 0; rt < 4; ++rt) {
            f16x8 af[4];
            #pragma unroll
            for (int kt = 0; kt < 4; ++kt) af[kt] = *(const f16x8*)&A[rt * 16 + lrow][kt * 32 + kq];
            f32x4 a0 = (f32x4){b0, b0, b0, b0}, a1 = (f32x4){b1, b1, b1, b1};
            #pragma unroll
            for (int kt = 0; kt < 4; ++kt) {
                a0 = __builtin_amdgcn_mfma_f32_16x16x32_f16(af[kt], bf0[kt], a0, 0, 0, 0);
                a1 = __builtin_amdgcn_mfma_f32_16x16x32_f16(af[kt], bf1[kt], a1, 0, 0, 0);
            }
            #pragma unroll
            for (int r = 0; r < 4; ++r) {
                H[rt * 16 + csub + r][nt0 * 16 + ccol] = (_Float16)fmaxf(a0[r], 0.f);
                H[rt * 16 + csub + r][nt1 * 16 + ccol] = (_Float16)fmaxf(a1[r], 0.f);
            }
        }
    }
    __syncthreads();

    // ---- GEMM2: H @ W1b + b1b, relu -> A ----
    {
        f16x8 bf0[4], bf1[4];
        #pragma unroll
        for (int kt = 0; kt < 4; ++kt) {
            bf0[kt] = *(const f16x8*)(Pb + ((size_t)((kt << 3) + nt0) * 64 + l) * 8);
            bf1[kt] = *(const f16x8*)(Pb + ((size_t)((kt << 3) + nt1) * 64 + l) * 8);
        }
        float b0 = b1b[nt0 * 16 + ccol], b1 = b1b[nt1 * 16 + ccol];
        #pragma unroll
        for (int rt = 0; rt < 4; ++rt) {
            f16x8 af[4];
            #pragma unroll
            for (int kt = 0; kt < 4; ++kt) af[kt] = *(const f16x8*)&H[rt * 16 + lrow][kt * 32 + kq];
            f32x4 a0 = (f32x4){b0, b0, b0, b0}, a1 = (f32x4){b1, b1, b1, b1};
            #pragma unroll
            for (int kt = 0; kt < 4; ++kt) {
                a0 = __builtin_amdgcn_mfma_f32_16x16x32_f16(af[kt], bf0[kt], a0, 0, 0, 0);
                a1 = __builtin_amdgcn_mfma_f32_16x16x32_f16(af[kt], bf1[kt], a1, 0, 0, 0);
            }
            #pragma unroll
            for (int r = 0; r < 4; ++r) {
                A[rt * 16 + csub + r][nt0 * 16 + ccol] = (_Float16)fmaxf(a0[r], 0.f);
                A[rt * 16 + csub + r][nt1 * 16 + ccol] = (_Float16)fmaxf(a1[r], 0.f);
            }
        }
    }
    __syncthreads();

    // ---- GEMM3: x2 @ W2a (bias deferred past aggregation) -> y fp16 ----
    // 12 tile-tasks (3 col-tiles x 4 row-tiles) over 4 waves, 3 tasks each (no idle wave)
    #pragma unroll
    for (int it = 0; it < 3; ++it) {
        int tt = w + 4 * it;           // 0..11
        int nt = tt % 3, rt = tt / 3;
        f16x8 bf[4], af[4];
        #pragma unroll
        for (int kt = 0; kt < 4; ++kt) {
            bf[kt] = *(const f16x8*)(Pc + ((size_t)(kt * 3 + nt) * 64 + l) * 8);
            af[kt] = *(const f16x8*)&A[rt * 16 + lrow][kt * 32 + kq];
        }
        f32x4 ya = (f32x4){0.f, 0.f, 0.f, 0.f};
        #pragma unroll
        for (int kt = 0; kt < 4; ++kt)
            ya = __builtin_amdgcn_mfma_f32_16x16x32_f16(af[kt], bf[kt], ya, 0, 0, 0);
        int col = nt * 16 + ccol;
        if (col < NC) {
            #pragma unroll
            for (int r = 0; r < 4; ++r) {
                size_t gr = row0 + rt * 16 + csub + r;
                if (gr < N_NODES) y[gr * NC + col] = __float2half(ya[r]);
            }
        }
    }
}

// ---------------- z = y + segsum(y[src]); h2 = relu(z+b2a); out = softmax(h2@W2b+b2b) ----------------
// 24-edge dual-buffer pipeline. Group-sums combined via LDS f32 atomicAdd into h2s (replaces the
// 4-stage stride-5 shfl tree: -75 VALU instrs/wave on the bottleneck pipe; summation order change
// only -- edge order already arbitrary). Matvec uses precomputed paired W2b layout (Wq).
__global__ __launch_bounds__(256) void k_gather2(const __half* __restrict__ y, const int* __restrict__ rs,
                                                 const int* __restrict__ dg, const int* __restrict__ csr_src,
                                                 const float* __restrict__ b2a, const float4* __restrict__ Wq,
                                                 const float* __restrict__ b2b, float* __restrict__ out) {
    __shared__ float h2s[4][NC];
    int l = threadIdx.x & 63, wid = threadIdx.x >> 6;
    int n = __builtin_amdgcn_readfirstlane(blockIdx.x * 4 + wid);
    int g = l / 5, j = l - g * 5;            // g in 0..12 (lanes 60..63: g==12 -> zero row)
    const uint4* y4 = (const uint4*)y;

    float acc[8] = {0.f, 0.f, 0.f, 0.f, 0.f, 0.f, 0.f, 0.f};
    // self row via group 0 (issued first; independent of the loop chain)
    uint4 self;
    if (l < 5) self = y4[(size_t)n * 5 + j];

    // h2s init with b2a (accumulation target for LDS atomics)
    if (l < NC) h2s[wid][l] = b2a[l];

    int i0 = rs[n], d = dg[n];
    int e = i0 + d;
    // prologue: both 12-edge batches issued back-to-back (invalid lanes -> zero row, L1-hot)
    uint4 c0, c1;
    {
        int iA = i0 + g;
        int sA = (g < 12 && iA < e) ? csr_src[iA] : N_NODES;
        c0 = y4[(size_t)sA * 5 + j];
        int iB = i0 + 12 + g;
        int sB = (g < 12 && iB < e) ? csr_src[iB] : N_NODES;
        c1 = y4[(size_t)sB * 5 + j];
    }
    int niter = (d + 23) / 24;               // 0 if isolated node
    for (int k = 1; k < niter; ++k) {        // rare: deg > 24 (~2% of nodes)
        int base = i0 + k * 24;
        int iA = base + g;
        int sA = (g < 12 && iA < e) ? csr_src[iA] : N_NODES;
        uint4 n0 = y4[(size_t)sA * 5 + j];
        int iB = base + 12 + g;
        int sB = (g < 12 && iB < e) ? csr_src[iB] : N_NODES;
        uint4 n1 = y4[(size_t)sB * 5 + j];   // issued before c0/c1 consumed
        acc_row8(acc, c0); c0 = n0;
        acc_row8(acc, c1); c1 = n1;
    }
    if (d > 0) {
        acc_row8(acc, c0);
        acc_row8(acc, c1);
    }
    if (l < 5) acc_row8(acc, self);

    __threadfence_block();   // h2s init visible before atomics (same wave; DS order safety)
    if (l < 60) {            // g<12: each lane adds its 8 dims [8j, 8j+8)
        #pragma unroll
        for (int k = 0; k < 8; ++k) atomicAdd(&h2s[wid][j * 8 + k], acc[k]);
    }
    __threadfence_block();   // atomics drained before relu pass (same-wave LDS RAW)
    if (l < NC) h2s[wid][l] = fmaxf(h2s[wid][l], 0.f);
    __threadfence_block();

    float logit = -__builtin_inff();
    if (l < NC) {
        float4 a4 = {0.f, 0.f, 0.f, 0.f};
        #pragma unroll
        for (int q = 0; q < 10; ++q) {
            float4 h4 = *(const float4*)&h2s[wid][4 * q];   // LDS broadcast (same addr, all lanes)
            float4 w4 = Wq[q * NC + l];                     // coalesced dwordx4, L1-hot
            a4.x = fmaf(h4.x, w4.x, a4.x);
            a4.y = fmaf(h4.y, w4.y, a4.y);
            a4.z = fmaf(h4.z, w4.z, a4.z);
            a4.w = fmaf(h4.w, w4.w, a4.w);
        }
        logit = (a4.x + a4.y) + (a4.z + a4.w) + b2b[l];
    }
    float m = logit;
    #pragma unroll
    for (int d2 = 32; d2 >= 1; d2 >>= 1) m = fmaxf(m, __shfl_xor(m, d2, 64));
    float ev = (l < NC) ? __expf(logit - m) : 0.f;
    float s = ev;
    #pragma unroll
    for (int d2 = 32; d2 >= 1; d2 >>= 1) s += __shfl_xor(s, d2, 64);
    if (l < NC) out[(size_t)n * NC + l] = ev / s;
}

extern "C" void kernel_launch(void* const* d_in, const int* in_sizes, int n_in,
                              void* d_out, int out_size, void* d_ws, size_t ws_size,
                              hipStream_t stream) {
    const float* x   = (const float*)d_in[0];
    const int2*  ei  = (const int2*)d_in[1];
    const float* W1a = (const float*)d_in[2];
    const float* b1a = (const float*)d_in[3];
    const float* W1b = (const float*)d_in[4];
    const float* b1b = (const float*)d_in[5];
    const float* W2a = (const float*)d_in[6];
    const float* b2a = (const float*)d_in[7];
    const float* W2b = (const float*)d_in[8];
    const float* b2b = (const float*)d_in[9];
    float* out = (float*)d_out;

    char* w = (char*)d_ws;
    int*    dg     = (int*)(w + 0);             // 100000 ints (degree; written by k_mid/csr_local)
    int*    cnt    = (int*)(w + 400000);        // 782 ints (segment cursors, memset 0)
    int*    rs     = (int*)(w + 403200);        // 100000 ints (node csr base, segment space)
    int*    csr    = (int*)(w + 803200);        // 782*3072 ints = 9.6MB (padded segment CSR)
    __half* xh     = (__half*)(w + 10412416);   // (100000+1)x128 fp16 (incl. zero row)
    __half* hp     = (__half*)(w + 36012672);   // 100000x128 fp16 (agg result)
    __half* y      = (__half*)(w + 61612672);   // (100000+1)x40 fp16 (incl. zero row)
    _Float16* Pa   = (_Float16*)(w + 69612800); // 32KB W1a frags
    _Float16* Pb   = (_Float16*)(w + 69645568); // 32KB W1b frags
    _Float16* Pc   = (_Float16*)(w + 69678336); // 12KB W2a frags (padded to 48 cols)
    float4*   Wq   = (float4*)(w + 69690624);   // 6.4KB W2b paired (10 x 40 float4)
    int*    seg    = (int*)hp;                  // 9.6MB segments OVERLAY hp (dead until gather1)
    // total ws needed: 69,697,024 bytes

    (void)hipMemsetAsync(w + 400000, 0, 3200, stream);  // zero cnt only
    k_binfill  <<<NBLK_FILL, 256, 0, stream>>>(ei, cnt, seg);
    k_mid      <<<NBUCKET + NBLK_CVT + NBLK_PACK, 256, 0, stream>>>(dg, cnt, seg, rs, csr,
                                                                    x, xh, y, W1a, W1b, W2a, W2b,
                                                                    Pa, Pb, Pc, Wq);
    k_gather1  <<<N_NODES / 4, 256, 0, stream>>>(xh, rs, dg, csr, hp);
    k_mlp      <<<(N_NODES + 63) / 64, 256, 0, stream>>>(hp, Pa, Pb, Pc, b1a, b1b, y);
    k_gather2  <<<N_NODES / 4, 256, 0, stream>>>(y, rs, dg, csr, b2a, Wq, b2b, out);
}

// Round 12
// 297.078 us; speedup vs baseline: 1.6837x; 1.6837x over previous
//
#include <hip/hip_runtime.h>
#include <hip/hip_fp16.h>

#define N_NODES 100000
#define N_EDGES 1600000
#define DIM 128
#define NC 40

#define BUCKET_SHIFT 7
#define BUCKET_NODES 128
#define NBUCKET ((N_NODES + BUCKET_NODES - 1) / BUCKET_NODES)   // 782
#define SEGCAP 3072                                             // mean bucket load 2048, sigma 45
#define NBIN 1024                                               // padded bins for LDS scan
#define EPB 4096                                                // edges per binfill block
#define NBLK_FILL ((N_EDGES + EPB - 1) / EPB)                   // 391

#define NBLK_CVT (N_NODES * DIM / 8 / 256)                      // 6250
#define NBLK_PACK 20                                            // 16 W1a/W1b + 3 Pc + 1 Wq

typedef _Float16 f16x8 __attribute__((ext_vector_type(8)));
typedef float f32x4 __attribute__((ext_vector_type(4)));

// add 8 halves (as uint4) into acc[0..8)
__device__ __forceinline__ void acc_row8(float* acc, uint4 v) {
    __half2 h;
    float2 f;
    *(unsigned*)&h = v.x; f = __half22float2(h); acc[0] += f.x; acc[1] += f.y;
    *(unsigned*)&h = v.y; f = __half22float2(h); acc[2] += f.x; acc[3] += f.y;
    *(unsigned*)&h = v.z; f = __half22float2(h); acc[4] += f.x; acc[5] += f.y;
    *(unsigned*)&h = v.w; f = __half22float2(h); acc[6] += f.x; acc[7] += f.y;
}

// ---------------- binfill: LDS counting-sort edges by 128-node bucket -> fixed-cap segments ----
// staged entry: src | (dst_local << 17)  (src<2^17, dst_local<2^7)
// Block-local LDS atomics + ONE global atomic per non-empty bin per block.
// Launched FIRST (edge chain is the critical path; cvt/pack overlap later in k_mid).
__global__ __launch_bounds__(256) void k_binfill(const int2* __restrict__ ei, int* __restrict__ cnt,
                                                 int* __restrict__ seg) {
    __shared__ int hist[NBIN];
    __shared__ int offs[NBIN];
    __shared__ int gbase[NBIN];
    __shared__ int lcnt[NBIN];
    __shared__ int lds[EPB];
    __shared__ short binof[EPB];   // bin id per staged slot (no phase-5 binary search)
    __shared__ int wt[4];
    int t = threadIdx.x;
    int e0 = blockIdx.x * EPB;
    int bec = N_EDGES - e0; if (bec > EPB) bec = EPB;

    // edge register cache (issued before LDS init; hides latency)
    int2 er[EPB / 256];
    #pragma unroll
    for (int k = 0; k < EPB / 256; ++k) {
        int i = e0 + t + k * 256;
        er[k] = (i < N_EDGES) ? ei[i] : (int2){0, -1};   // y = -1 -> invalid lane
    }

    #pragma unroll
    for (int j = 0; j < NBIN / 256; ++j) { hist[t + j * 256] = 0; lcnt[t + j * 256] = 0; }
    __syncthreads();

    // phase 1: histogram
    #pragma unroll
    for (int k = 0; k < EPB / 256; ++k)
        if (er[k].y >= 0) atomicAdd(&hist[er[k].y >> BUCKET_SHIFT], 1);
    __syncthreads();

    // phase 2: exclusive scan of hist[1024]
    int lane = t & 63, w = t >> 6;
    int h[4], p = 0;
    #pragma unroll
    for (int j = 0; j < 4; ++j) { h[j] = hist[t * 4 + j]; p += h[j]; }
    int inc = p;
    #pragma unroll
    for (int d = 1; d < 64; d <<= 1) {
        int u = __shfl_up(inc, d, 64);
        if (lane >= d) inc += u;
    }
    if (lane == 63) wt[w] = inc;
    __syncthreads();
    int add = inc - p;
    for (int k = 0; k < w; ++k) add += wt[k];
    int run = add;
    #pragma unroll
    for (int j = 0; j < 4; ++j) { offs[t * 4 + j] = run; run += h[j]; }
    __syncthreads();

    // phase 3: reserve segment ranges (one atomic per non-empty bin)
    #pragma unroll
    for (int j = 0; j < 4; ++j) {
        int b = t * 4 + j;
        if (b < NBUCKET && h[j] > 0) gbase[b] = b * SEGCAP + atomicAdd(&cnt[b], h[j]);
    }
    __syncthreads();

    // phase 4: scatter packed edges into LDS in bin order (+ record bin per slot)
    #pragma unroll
    for (int k = 0; k < EPB / 256; ++k) {
        if (er[k].y >= 0) {
            int b = er[k].y >> BUCKET_SHIFT;
            int pos = offs[b] + atomicAdd(&lcnt[b], 1);
            lds[pos] = er[k].x | ((er[k].y & (BUCKET_NODES - 1)) << 17);
            binof[pos] = (short)b;
        }
    }
    __syncthreads();

    // phase 5: coalesced write-out (bin of position i read directly)
    for (int i = t; i < bec; i += 256) {
        int lo = binof[i];
        seg[gbase[lo] + (i - offs[lo])] = lds[i];
    }
}

// ---------------- k_mid: csr_local (782 blocks) || x->fp16 cvt (6250) || weight pack (20) ----------
// csr_local depends on binfill; cvt/pack are independent -> overlapped in one dispatch (saves a
// dispatch AND takes cvt off the critical path). LDS = 1KB (csr_local) so cvt occupancy unharmed.
__global__ __launch_bounds__(256) void k_mid(int* __restrict__ dg, const int* __restrict__ cnt,
                                             const int* __restrict__ seg, int* __restrict__ rs,
                                             int* __restrict__ csr,
                                             const float* __restrict__ x, __half* __restrict__ xh,
                                             __half* __restrict__ y,
                                             const float* __restrict__ W1a, const float* __restrict__ W1b,
                                             const float* __restrict__ W2a, const float* __restrict__ W2b,
                                             _Float16* __restrict__ Pa, _Float16* __restrict__ Pb,
                                             _Float16* __restrict__ Pc, float4* __restrict__ Wq) {
    __shared__ int ldg[BUCKET_NODES];
    __shared__ int cur[BUCKET_NODES];
    __shared__ int wq0;
    int b = blockIdx.x, t = threadIdx.x;

    if (b < NBUCKET) {
        // ---- per-bucket CSR fill: LDS degree hist + local prefix + scatter in 12KB window ----
        int n0 = b * BUCKET_NODES;
        int nn = N_NODES - n0; if (nn > BUCKET_NODES) nn = BUCKET_NODES;
        if (t < BUCKET_NODES) ldg[t] = 0;
        __syncthreads();

        int c = cnt[b];
        // pass 1: per-node degree histogram (LDS atomics)
        for (int i = t; i < c; i += 256)
            atomicAdd(&ldg[(seg[b * SEGCAP + i] >> 17) & (BUCKET_NODES - 1)], 1);
        __syncthreads();

        // local exclusive scan of ldg[0..128) (threads 0..127 over 2 waves)
        int d = (t < BUCKET_NODES) ? ldg[t] : 0;
        int lane = t & 63, w2 = t >> 6;
        int incl = d;
        #pragma unroll
        for (int s = 1; s < 64; s <<= 1) {
            int u = __shfl_up(incl, s, 64);
            if (lane >= s) incl += u;
        }
        if (w2 == 0 && lane == 63) wq0 = incl;
        __syncthreads();
        int excl = incl - d + ((w2 == 1) ? wq0 : 0);
        if (t < nn) {
            int base = b * SEGCAP + excl;
            cur[t] = base;
            rs[n0 + t] = base;
            dg[n0 + t] = d;
        }
        __syncthreads();

        // pass 2: scatter (seg L2-hot from pass 1)
        for (int i = t; i < c; i += 256) {
            int e = seg[b * SEGCAP + i];
            int dl = (e >> 17) & (BUCKET_NODES - 1);
            int pos = atomicAdd(&cur[dl], 1);
            csr[pos] = e & 0x1FFFF;
        }
        return;
    }

    int cb = b - NBUCKET;
    if (cb < NBLK_CVT) {
        // ---- x -> fp16 convert + zero-row init ----
        int i = cb * 256 + t;                        // 6250*256*8 == N_NODES*DIM exactly
        if (cb == 0) {
            if (t < 16) ((uint4*)xh)[(size_t)N_NODES * (DIM / 8) + t] = (uint4){0, 0, 0, 0};
            else if (t < 21) ((uint4*)y)[(size_t)N_NODES * 5 + t - 16] = (uint4){0, 0, 0, 0};
        }
        float4 v0 = ((const float4*)x)[(size_t)i * 2];
        float4 v1 = ((const float4*)x)[(size_t)i * 2 + 1];
        __half2 h01 = __float22half2_rn(make_float2(v0.x, v0.y));
        __half2 h23 = __float22half2_rn(make_float2(v0.z, v0.w));
        __half2 h45 = __float22half2_rn(make_float2(v1.x, v1.y));
        __half2 h67 = __float22half2_rn(make_float2(v1.z, v1.w));
        uint4 o;
        o.x = *(unsigned*)&h01; o.y = *(unsigned*)&h23;
        o.z = *(unsigned*)&h45; o.w = *(unsigned*)&h67;
        ((uint4*)xh)[i] = o;
        return;
    }

    // ---- pack path: W1a/W1b (128x128) and W2a (128x40->48) into fp16 MFMA B-frags; W2b pairs ----
    int bid = cb - NBLK_CVT;
    if (bid < 16) {
        const float* W = (bid < 8) ? W1a : W1b;
        _Float16* P = (bid < 8) ? Pa : Pb;
        int tt = (bid & 7) * 256 + t;           // 0..2047
        int l = tt & 63, nt = (tt >> 6) & 7, kt = tt >> 9;
        int n = nt * 16 + (l & 15);
        int kb = kt * 32 + (l >> 4) * 8;
        #pragma unroll
        for (int j = 0; j < 8; ++j)
            P[(size_t)tt * 8 + j] = (_Float16)W[(size_t)(kb + j) * DIM + n];
    } else if (bid < 19) {
        int tt = (bid - 16) * 256 + t;          // 0..767
        if (tt < 768) {
            int l = tt & 63, u = tt >> 6;        // u = kt*3 + nt
            int nt = u % 3, kt = u / 3;
            int n = nt * 16 + (l & 15);
            int kb = kt * 32 + (l >> 4) * 8;
            #pragma unroll
            for (int j = 0; j < 8; ++j) {
                float wv = (n < NC) ? W2a[(size_t)(kb + j) * NC + n] : 0.f;
                Pc[(size_t)tt * 8 + j] = (_Float16)wv;
            }
        }
    } else {
        // Wq[q*NC + l] = {W2b[4q+0][l], W2b[4q+1][l], W2b[4q+2][l], W2b[4q+3][l]}  (exact f32 copy)
        for (int u = t; u < 10 * NC; u += 256) {
            int q = u / NC, c = u - q * NC;
            float4 wv;
            wv.x = W2b[(4 * q + 0) * NC + c];
            wv.y = W2b[(4 * q + 1) * NC + c];
            wv.z = W2b[(4 * q + 2) * NC + c];
            wv.w = W2b[(4 * q + 3) * NC + c];
            Wq[u] = wv;
        }
    }
}

// ---------------- layer 1 aggregation: hp = x + segsum(x[src]) ----------------
// Four rows per VMEM instruction: 16-lane group g (16 x uint4 = 256 B) loads row s[g].
// Dual-buffer software pipeline: batch k+1's csr+row loads issue before batch k is consumed.
__global__ __launch_bounds__(256) void k_gather1(const __half* __restrict__ xh, const int* __restrict__ rs,
                                                 const int* __restrict__ dg, const int* __restrict__ csr_src,
                                                 __half* __restrict__ hp) {
    int l = threadIdx.x & 63, wid = threadIdx.x >> 6;
    int n = __builtin_amdgcn_readfirstlane(blockIdx.x * 4 + wid);
    int grp = l >> 4, q = l & 15;
    const uint4* x4 = (const uint4*)xh;            // row stride: 16 uint4

    // self row issued early (lanes 0..15; consumed after the loop)
    uint4 sv;
    if (grp == 0) sv = x4[(size_t)n * 16 + q];

    float acc[8] = {0.f, 0.f, 0.f, 0.f, 0.f, 0.f, 0.f, 0.f};
    int i0 = rs[n], e = i0 + dg[n];
    int niter = (e - i0 + 7) >> 3;
    uint4 cur[2];
    if (niter > 0) {
        #pragma unroll
        for (int u = 0; u < 2; ++u) {
            int idx = i0 + u * 4 + grp;
            int s = (idx < e) ? csr_src[idx] : N_NODES;   // N_NODES = zero row (L1-hot)
            cur[u] = x4[(size_t)s * 16 + q];
        }
    }
    for (int k = 1; k < niter; ++k) {
        int base = i0 + k * 8;
        uint4 nxt[2];
        #pragma unroll
        for (int u = 0; u < 2; ++u) {
            int idx = base + u * 4 + grp;
            int s = (idx < e) ? csr_src[idx] : N_NODES;
            nxt[u] = x4[(size_t)s * 16 + q];              // issued before cur is consumed
        }
        acc_row8(acc, cur[0]); cur[0] = nxt[0];
        acc_row8(acc, cur[1]); cur[1] = nxt[1];
    }
    if (niter > 0) {
        acc_row8(acc, cur[0]);
        acc_row8(acc, cur[1]);
    }
    // combine the 4 groups (lanes l, l^16, l^32, l^48 hold the same 8 dims)
    #pragma unroll
    for (int k2 = 0; k2 < 8; ++k2) {
        acc[k2] += __shfl_xor(acc[k2], 16);
        acc[k2] += __shfl_xor(acc[k2], 32);
    }

    if (grp == 0) {
        acc_row8(acc, sv);   // add self row
        __half2 o0 = __float22half2_rn(make_float2(acc[0], acc[1]));
        __half2 o1 = __float22half2_rn(make_float2(acc[2], acc[3]));
        __half2 o2 = __float22half2_rn(make_float2(acc[4], acc[5]));
        __half2 o3 = __float22half2_rn(make_float2(acc[6], acc[7]));
        uint4 ov;
        ov.x = *(unsigned*)&o0; ov.y = *(unsigned*)&o1;
        ov.z = *(unsigned*)&o2; ov.w = *(unsigned*)&o3;
        ((uint4*)hp)[(size_t)n * 16 + q] = ov;
    }
}

// ---------------- fused MLP via fp16 MFMA: y = relu(relu(hp@W1a+b1a)@W1b+b1b) @ W2a ----------------
// Column-split waves: wave w owns col-tiles {2w,2w+1} for ALL 4 row-tiles (GEMM1/2).
// B-frags load ONCE per wave into registers; A-frags re-read from LDS per row-tile.
// GEMM3: 12 tile-tasks round-robined on 4 waves.
__global__ __launch_bounds__(256) void k_mlp(const __half* __restrict__ hp,
    const _Float16* __restrict__ Pa, const _Float16* __restrict__ Pb, const _Float16* __restrict__ Pc,
    const float* __restrict__ b1a, const float* __restrict__ b1b, __half* __restrict__ y) {
    __shared__ _Float16 A[64][136];   // +8 pad (16B): aligned frag reads
    __shared__ _Float16 H[64][136];
    int t = threadIdx.x;
    size_t row0 = (size_t)blockIdx.x * 64;

    for (int i = t; i < 1024; i += 256) {
        int r = i >> 4, c = i & 15;
        size_t g = row0 + r;
        if (g >= N_NODES) g = N_NODES - 1;    // clamped read; stores guarded below
        uint4 v = ((const uint4*)(hp + g * DIM))[c];
        *(uint4*)&A[r][c * 8] = v;
    }
    __syncthreads();

    int w = t >> 6, l = t & 63;
    int lrow = l & 15;                 // A-frag row within tile
    int kq = (l >> 4) * 8;
    int csub = (l >> 4) * 4;           // C-layout row sub-base
    int ccol = l & 15;
    int nt0 = 2 * w, nt1 = 2 * w + 1;

    // ---- GEMM1: A @ W1a + b1a, relu -> H  (wave w: cols [32w, 32w+32)) ----
    {
        f16x8 bf0[4], bf1[4];
        #pragma unroll
        for (int kt = 0; kt < 4; ++kt) {
            bf0[kt] = *(const f16x8*)(Pa + ((size_t)((kt << 3) + nt0) * 64 + l) * 8);
            bf1[kt] = *(const f16x8*)(Pa + ((size_t)((kt << 3) + nt1) * 64 + l) * 8);
        }
        float b0 = b1a[nt0 * 16 + ccol], b1 = b1a[nt1 * 16 + ccol];
        #pragma unroll
        for (int rt = 0; rt < 4; ++rt) {
            f16x8 af[4];
            #pragma unroll
            for (int kt = 0; kt < 4; ++kt) af[kt] = *(const f16x8*)&A[rt * 16 + lrow][kt * 32 + kq];
            f32x4 a0 = (f32x4){b0, b0, b0, b0}, a1 = (f32x4){b1, b1, b1, b1};
            #pragma unroll
            for (int kt = 0; kt < 4; ++kt) {
                a0 = __builtin_amdgcn_mfma_f32_16x16x32_f16(af[kt], bf0[kt], a0, 0, 0, 0);
                a1 = __builtin_amdgcn_mfma_f32_16x16x32_f16(af[kt], bf1[kt], a1, 0, 0, 0);
            }
            #pragma unroll
            for (int r = 0; r < 4; ++r) {
                H[rt * 16 + csub + r][nt0 * 16 + ccol] = (_Float16)fmaxf(a0[r], 0.f);
                H[rt * 16 + csub + r][nt1 * 16 + ccol] = (_Float16)fmaxf(a1[r], 0.f);
            }
        }
    }
    __syncthreads();

    // ---- GEMM2: H @ W1b + b1b, relu -> A ----
    {
        f16x8 bf0[4], bf1[4];
        #pragma unroll
        for (int kt = 0; kt < 4; ++kt) {
            bf0[kt] = *(const f16x8*)(Pb + ((size_t)((kt << 3) + nt0) * 64 + l) * 8);
            bf1[kt] = *(const f16x8*)(Pb + ((size_t)((kt << 3) + nt1) * 64 + l) * 8);
        }
        float b0 = b1b[nt0 * 16 + ccol], b1 = b1b[nt1 * 16 + ccol];
        #pragma unroll
        for (int rt = 0; rt < 4; ++rt) {
            f16x8 af[4];
            #pragma unroll
            for (int kt = 0; kt < 4; ++kt) af[kt] = *(const f16x8*)&H[rt * 16 + lrow][kt * 32 + kq];
            f32x4 a0 = (f32x4){b0, b0, b0, b0}, a1 = (f32x4){b1, b1, b1, b1};
            #pragma unroll
            for (int kt = 0; kt < 4; ++kt) {
                a0 = __builtin_amdgcn_mfma_f32_16x16x32_f16(af[kt], bf0[kt], a0, 0, 0, 0);
                a1 = __builtin_amdgcn_mfma_f32_16x16x32_f16(af[kt], bf1[kt], a1, 0, 0, 0);
            }
            #pragma unroll
            for (int r = 0; r < 4; ++r) {
                A[rt * 16 + csub + r][nt0 * 16 + ccol] = (_Float16)fmaxf(a0[r], 0.f);
                A[rt * 16 + csub + r][nt1 * 16 + ccol] = (_Float16)fmaxf(a1[r], 0.f);
            }
        }
    }
    __syncthreads();

    // ---- GEMM3: x2 @ W2a (bias deferred past aggregation) -> y fp16 ----
    // 12 tile-tasks (3 col-tiles x 4 row-tiles) over 4 waves, 3 tasks each (no idle wave)
    #pragma unroll
    for (int it = 0; it < 3; ++it) {
        int tt = w + 4 * it;           // 0..11
        int nt = tt % 3, rt = tt / 3;
        f16x8 bf[4], af[4];
        #pragma unroll
        for (int kt = 0; kt < 4; ++kt) {
            bf[kt] = *(const f16x8*)(Pc + ((size_t)(kt * 3 + nt) * 64 + l) * 8);
            af[kt] = *(const f16x8*)&A[rt * 16 + lrow][kt * 32 + kq];
        }
        f32x4 ya = (f32x4){0.f, 0.f, 0.f, 0.f};
        #pragma unroll
        for (int kt = 0; kt < 4; ++kt)
            ya = __builtin_amdgcn_mfma_f32_16x16x32_f16(af[kt], bf[kt], ya, 0, 0, 0);
        int col = nt * 16 + ccol;
        if (col < NC) {
            #pragma unroll
            for (int r = 0; r < 4; ++r) {
                size_t gr = row0 + rt * 16 + csub + r;
                if (gr < N_NODES) y[gr * NC + col] = __float2half(ya[r]);
            }
        }
    }
}

// ---------------- z = y + segsum(y[src]); h2 = relu(z+b2a); out = softmax(h2@W2b+b2b) ----------------
// 24-edge dual-buffer pipeline (two 12-wide row-load batches in flight): for deg<=24 (97% of
// nodes) the loop body never executes. Stride-5 shfl tree (r10-proven; the r11 LDS-atomic variant
// serialized 12-way on the DS pipe and was 4x slower). Matvec uses paired W2b layout (Wq).
__global__ __launch_bounds__(256) void k_gather2(const __half* __restrict__ y, const int* __restrict__ rs,
                                                 const int* __restrict__ dg, const int* __restrict__ csr_src,
                                                 const float* __restrict__ b2a, const float4* __restrict__ Wq,
                                                 const float* __restrict__ b2b, float* __restrict__ out) {
    __shared__ float h2s[4][NC];
    int l = threadIdx.x & 63, wid = threadIdx.x >> 6;
    int n = __builtin_amdgcn_readfirstlane(blockIdx.x * 4 + wid);
    int g = l / 5, j = l - g * 5;            // g in 0..12 (lanes 60..63: g==12 -> zero row)
    const uint4* y4 = (const uint4*)y;

    float acc[8] = {0.f, 0.f, 0.f, 0.f, 0.f, 0.f, 0.f, 0.f};
    // self row via group 0 (issued first; independent of the loop chain)
    uint4 self;
    if (l < 5) self = y4[(size_t)n * 5 + j];

    int i0 = rs[n], d = dg[n];
    int e = i0 + d;
    // prologue: both 12-edge batches issued back-to-back (invalid lanes -> zero row, L1-hot)
    uint4 c0, c1;
    {
        int iA = i0 + g;
        int sA = (g < 12 && iA < e) ? csr_src[iA] : N_NODES;
        c0 = y4[(size_t)sA * 5 + j];
        int iB = i0 + 12 + g;
        int sB = (g < 12 && iB < e) ? csr_src[iB] : N_NODES;
        c1 = y4[(size_t)sB * 5 + j];
    }
    int niter = (d + 23) / 24;               // 0 if isolated node
    for (int k = 1; k < niter; ++k) {        // rare: deg > 24 (~2% of nodes)
        int base = i0 + k * 24;
        int iA = base + g;
        int sA = (g < 12 && iA < e) ? csr_src[iA] : N_NODES;
        uint4 n0 = y4[(size_t)sA * 5 + j];
        int iB = base + 12 + g;
        int sB = (g < 12 && iB < e) ? csr_src[iB] : N_NODES;
        uint4 n1 = y4[(size_t)sB * 5 + j];   // issued before c0/c1 consumed
        acc_row8(acc, c0); c0 = n0;
        acc_row8(acc, c1); c1 = n1;
    }
    if (d > 0) {
        acc_row8(acc, c0);
        acc_row8(acc, c1);
    }
    if (l < 5) acc_row8(acc, self);

    #pragma unroll
    for (int k = 0; k < 8; ++k) acc[k] += __shfl_down(acc[k], 30);   // g += 6
    #pragma unroll
    for (int k = 0; k < 8; ++k) acc[k] += __shfl_down(acc[k], 15);   // g += 3
    #pragma unroll
    for (int k = 0; k < 8; ++k) acc[k] += __shfl_down(acc[k], 5) + __shfl_down(acc[k], 10);

    if (l < 5) {
        float4 b0 = *(const float4*)(b2a + 8 * l);
        float4 b1 = *(const float4*)(b2a + 8 * l + 4);
        float4 h0, h1;
        h0.x = fmaxf(acc[0] + b0.x, 0.f); h0.y = fmaxf(acc[1] + b0.y, 0.f);
        h0.z = fmaxf(acc[2] + b0.z, 0.f); h0.w = fmaxf(acc[3] + b0.w, 0.f);
        h1.x = fmaxf(acc[4] + b1.x, 0.f); h1.y = fmaxf(acc[5] + b1.y, 0.f);
        h1.z = fmaxf(acc[6] + b1.z, 0.f); h1.w = fmaxf(acc[7] + b1.w, 0.f);
        *(float4*)&h2s[wid][8 * l] = h0;
        *(float4*)&h2s[wid][8 * l + 4] = h1;
    }
    __threadfence_block();   // same-wave LDS RAW only (each wave owns h2s[wid])

    float logit = -__builtin_inff();
    if (l < NC) {
        float4 a4 = {0.f, 0.f, 0.f, 0.f};
        #pragma unroll
        for (int q = 0; q < 10; ++q) {
            float4 h4 = *(const float4*)&h2s[wid][4 * q];   // LDS broadcast (same addr, all lanes)
            float4 w4 = Wq[q * NC + l];                     // coalesced dwordx4, L1-hot
            a4.x = fmaf(h4.x, w4.x, a4.x);
            a4.y = fmaf(h4.y, w4.y, a4.y);
            a4.z = fmaf(h4.z, w4.z, a4.z);
            a4.w = fmaf(h4.w, w4.w, a4.w);
        }
        logit = (a4.x + a4.y) + (a4.z + a4.w) + b2b[l];
    }
    float m = logit;
    #pragma unroll
    for (int d2 = 32; d2 >= 1; d2 >>= 1) m = fmaxf(m, __shfl_xor(m, d2, 64));
    float ev = (l < NC) ? __expf(logit - m) : 0.f;
    float s = ev;
    #pragma unroll
    for (int d2 = 32; d2 >= 1; d2 >>= 1) s += __shfl_xor(s, d2, 64);
    if (l < NC) out[(size_t)n * NC + l] = ev / s;
}

extern "C" void kernel_launch(void* const* d_in, const int* in_sizes, int n_in,
                              void* d_out, int out_size, void* d_ws, size_t ws_size,
                              hipStream_t stream) {
    const float* x   = (const float*)d_in[0];
    const int2*  ei  = (const int2*)d_in[1];
    const float* W1a = (const float*)d_in[2];
    const float* b1a = (const float*)d_in[3];
    const float* W1b = (const float*)d_in[4];
    const float* b1b = (const float*)d_in[5];
    const float* W2a = (const float*)d_in[6];
    const float* b2a = (const float*)d_in[7];
    const float* W2b = (const float*)d_in[8];
    const float* b2b = (const float*)d_in[9];
    float* out = (float*)d_out;

    char* w = (char*)d_ws;
    int*    dg     = (int*)(w + 0);             // 100000 ints (degree; written by k_mid/csr_local)
    int*    cnt    = (int*)(w + 400000);        // 782 ints (segment cursors, memset 0)
    int*    rs     = (int*)(w + 403200);        // 100000 ints (node csr base, segment space)
    int*    csr    = (int*)(w + 803200);        // 782*3072 ints = 9.6MB (padded segment CSR)
    __half* xh     = (__half*)(w + 10412416);   // (100000+1)x128 fp16 (incl. zero row)
    __half* hp     = (__half*)(w + 36012672);   // 100000x128 fp16 (agg result)
    __half* y      = (__half*)(w + 61612672);   // (100000+1)x40 fp16 (incl. zero row)
    _Float16* Pa   = (_Float16*)(w + 69612800); // 32KB W1a frags
    _Float16* Pb   = (_Float16*)(w + 69645568); // 32KB W1b frags
    _Float16* Pc   = (_Float16*)(w + 69678336); // 12KB W2a frags (padded to 48 cols)
    float4*   Wq   = (float4*)(w + 69690624);   // 6.4KB W2b paired (10 x 40 float4)
    int*    seg    = (int*)hp;                  // 9.6MB segments OVERLAY hp (dead until gather1)
    // total ws needed: 69,697,024 bytes

    (void)hipMemsetAsync(w + 400000, 0, 3200, stream);  // zero cnt only
    k_binfill  <<<NBLK_FILL, 256, 0, stream>>>(ei, cnt, seg);
    k_mid      <<<NBUCKET + NBLK_CVT + NBLK_PACK, 256, 0, stream>>>(dg, cnt, seg, rs, csr,
                                                                    x, xh, y, W1a, W1b, W2a, W2b,
                                                                    Pa, Pb, Pc, Wq);
    k_gather1  <<<N_NODES / 4, 256, 0, stream>>>(xh, rs, dg, csr, hp);
    k_mlp      <<<(N_NODES + 63) / 64, 256, 0, stream>>>(hp, Pa, Pb, Pc, b1a, b1b, y);
    k_gather2  <<<N_NODES / 4, 256, 0, stream>>>(y, rs, dg, csr, b2a, Wq, b2b, out);
}

// Round 13
// 296.995 us; speedup vs baseline: 1.6842x; 1.0003x over previous
//
#include <hip/hip_runtime.h>
#include <hip/hip_fp16.h>

#define N_NODES 100000
#define N_EDGES 1600000
#define DIM 128
#define NC 40

#define BUCKET_SHIFT 7
#define BUCKET_NODES 128
#define NBUCKET ((N_NODES + BUCKET_NODES - 1) / BUCKET_NODES)   // 782
#define SEGCAP 3072                                             // mean bucket load 2048, sigma 45
#define NBIN 1024                                               // padded bins for LDS scan
#define EPB 4096                                                // edges per binfill block
#define NBLK_FILL ((N_EDGES + EPB - 1) / EPB)                   // 391

#define NBLK_CVT (N_NODES * DIM / 8 / 256)                      // 6250
#define NBLK_PACK 20                                            // 16 W1a/W1b + 3 Pc + 1 Wq

typedef _Float16 f16x8 __attribute__((ext_vector_type(8)));
typedef float f32x4 __attribute__((ext_vector_type(4)));

// add 8 halves (as uint4) into acc[0..8)
__device__ __forceinline__ void acc_row8(float* acc, uint4 v) {
    __half2 h;
    float2 f;
    *(unsigned*)&h = v.x; f = __half22float2(h); acc[0] += f.x; acc[1] += f.y;
    *(unsigned*)&h = v.y; f = __half22float2(h); acc[2] += f.x; acc[3] += f.y;
    *(unsigned*)&h = v.z; f = __half22float2(h); acc[4] += f.x; acc[5] += f.y;
    *(unsigned*)&h = v.w; f = __half22float2(h); acc[6] += f.x; acc[7] += f.y;
}

// add 4 halves (as uint2) into acc[0..4)
__device__ __forceinline__ void acc_row4(float* acc, uint2 v) {
    __half2 h;
    float2 f;
    *(unsigned*)&h = v.x; f = __half22float2(h); acc[0] += f.x; acc[1] += f.y;
    *(unsigned*)&h = v.y; f = __half22float2(h); acc[2] += f.x; acc[3] += f.y;
}

// ---------------- binfill: LDS counting-sort edges by 128-node bucket -> fixed-cap segments ----
// staged entry: src | (dst_local << 17)  (src<2^17, dst_local<2^7)
// Block-local LDS atomics + ONE global atomic per non-empty bin per block.
// Launched FIRST (edge chain is the critical path; cvt/pack overlap later in k_mid).
__global__ __launch_bounds__(256) void k_binfill(const int2* __restrict__ ei, int* __restrict__ cnt,
                                                 int* __restrict__ seg) {
    __shared__ int hist[NBIN];
    __shared__ int offs[NBIN];
    __shared__ int gbase[NBIN];
    __shared__ int lcnt[NBIN];
    __shared__ int lds[EPB];
    __shared__ short binof[EPB];   // bin id per staged slot (no phase-5 binary search)
    __shared__ int wt[4];
    int t = threadIdx.x;
    int e0 = blockIdx.x * EPB;
    int bec = N_EDGES - e0; if (bec > EPB) bec = EPB;

    // edge register cache (issued before LDS init; hides latency)
    int2 er[EPB / 256];
    #pragma unroll
    for (int k = 0; k < EPB / 256; ++k) {
        int i = e0 + t + k * 256;
        er[k] = (i < N_EDGES) ? ei[i] : (int2){0, -1};   // y = -1 -> invalid lane
    }

    #pragma unroll
    for (int j = 0; j < NBIN / 256; ++j) { hist[t + j * 256] = 0; lcnt[t + j * 256] = 0; }
    __syncthreads();

    // phase 1: histogram
    #pragma unroll
    for (int k = 0; k < EPB / 256; ++k)
        if (er[k].y >= 0) atomicAdd(&hist[er[k].y >> BUCKET_SHIFT], 1);
    __syncthreads();

    // phase 2: exclusive scan of hist[1024]
    int lane = t & 63, w = t >> 6;
    int h[4], p = 0;
    #pragma unroll
    for (int j = 0; j < 4; ++j) { h[j] = hist[t * 4 + j]; p += h[j]; }
    int inc = p;
    #pragma unroll
    for (int d = 1; d < 64; d <<= 1) {
        int u = __shfl_up(inc, d, 64);
        if (lane >= d) inc += u;
    }
    if (lane == 63) wt[w] = inc;
    __syncthreads();
    int add = inc - p;
    for (int k = 0; k < w; ++k) add += wt[k];
    int run = add;
    #pragma unroll
    for (int j = 0; j < 4; ++j) { offs[t * 4 + j] = run; run += h[j]; }
    __syncthreads();

    // phase 3: reserve segment ranges (one atomic per non-empty bin)
    #pragma unroll
    for (int j = 0; j < 4; ++j) {
        int b = t * 4 + j;
        if (b < NBUCKET && h[j] > 0) gbase[b] = b * SEGCAP + atomicAdd(&cnt[b], h[j]);
    }
    __syncthreads();

    // phase 4: scatter packed edges into LDS in bin order (+ record bin per slot)
    #pragma unroll
    for (int k = 0; k < EPB / 256; ++k) {
        if (er[k].y >= 0) {
            int b = er[k].y >> BUCKET_SHIFT;
            int pos = offs[b] + atomicAdd(&lcnt[b], 1);
            lds[pos] = er[k].x | ((er[k].y & (BUCKET_NODES - 1)) << 17);
            binof[pos] = (short)b;
        }
    }
    __syncthreads();

    // phase 5: coalesced write-out (bin of position i read directly)
    for (int i = t; i < bec; i += 256) {
        int lo = binof[i];
        seg[gbase[lo] + (i - offs[lo])] = lds[i];
    }
}

// ---------------- k_mid: csr_local (782 blocks) || x->fp16 cvt (6250) || weight pack (20) ----------
// csr_local depends on binfill; cvt/pack are independent -> overlapped in one dispatch (saves a
// dispatch AND takes cvt off the critical path). LDS = 1KB (csr_local) so cvt occupancy unharmed.
__global__ __launch_bounds__(256) void k_mid(int* __restrict__ dg, const int* __restrict__ cnt,
                                             const int* __restrict__ seg, int* __restrict__ rs,
                                             int* __restrict__ csr,
                                             const float* __restrict__ x, __half* __restrict__ xh,
                                             __half* __restrict__ y,
                                             const float* __restrict__ W1a, const float* __restrict__ W1b,
                                             const float* __restrict__ W2a, const float* __restrict__ W2b,
                                             _Float16* __restrict__ Pa, _Float16* __restrict__ Pb,
                                             _Float16* __restrict__ Pc, float4* __restrict__ Wq) {
    __shared__ int ldg[BUCKET_NODES];
    __shared__ int cur[BUCKET_NODES];
    __shared__ int wq0;
    int b = blockIdx.x, t = threadIdx.x;

    if (b < NBUCKET) {
        // ---- per-bucket CSR fill: LDS degree hist + local prefix + scatter in 12KB window ----
        int n0 = b * BUCKET_NODES;
        int nn = N_NODES - n0; if (nn > BUCKET_NODES) nn = BUCKET_NODES;
        if (t < BUCKET_NODES) ldg[t] = 0;
        __syncthreads();

        int c = cnt[b];
        // pass 1: per-node degree histogram (LDS atomics)
        for (int i = t; i < c; i += 256)
            atomicAdd(&ldg[(seg[b * SEGCAP + i] >> 17) & (BUCKET_NODES - 1)], 1);
        __syncthreads();

        // local exclusive scan of ldg[0..128) (threads 0..127 over 2 waves)
        int d = (t < BUCKET_NODES) ? ldg[t] : 0;
        int lane = t & 63, w2 = t >> 6;
        int incl = d;
        #pragma unroll
        for (int s = 1; s < 64; s <<= 1) {
            int u = __shfl_up(incl, s, 64);
            if (lane >= s) incl += u;
        }
        if (w2 == 0 && lane == 63) wq0 = incl;
        __syncthreads();
        int excl = incl - d + ((w2 == 1) ? wq0 : 0);
        if (t < nn) {
            int base = b * SEGCAP + excl;
            cur[t] = base;
            rs[n0 + t] = base;
            dg[n0 + t] = d;
        }
        __syncthreads();

        // pass 2: scatter (seg L2-hot from pass 1)
        for (int i = t; i < c; i += 256) {
            int e = seg[b * SEGCAP + i];
            int dl = (e >> 17) & (BUCKET_NODES - 1);
            int pos = atomicAdd(&cur[dl], 1);
            csr[pos] = e & 0x1FFFF;
        }
        return;
    }

    int cb = b - NBUCKET;
    if (cb < NBLK_CVT) {
        // ---- x -> fp16 convert + zero-row init ----
        int i = cb * 256 + t;                        // 6250*256*8 == N_NODES*DIM exactly
        if (cb == 0) {
            if (t < 16) ((uint4*)xh)[(size_t)N_NODES * (DIM / 8) + t] = (uint4){0, 0, 0, 0};
            else if (t < 21) ((uint4*)y)[(size_t)N_NODES * 5 + t - 16] = (uint4){0, 0, 0, 0};
        }
        float4 v0 = ((const float4*)x)[(size_t)i * 2];
        float4 v1 = ((const float4*)x)[(size_t)i * 2 + 1];
        __half2 h01 = __float22half2_rn(make_float2(v0.x, v0.y));
        __half2 h23 = __float22half2_rn(make_float2(v0.z, v0.w));
        __half2 h45 = __float22half2_rn(make_float2(v1.x, v1.y));
        __half2 h67 = __float22half2_rn(make_float2(v1.z, v1.w));
        uint4 o;
        o.x = *(unsigned*)&h01; o.y = *(unsigned*)&h23;
        o.z = *(unsigned*)&h45; o.w = *(unsigned*)&h67;
        ((uint4*)xh)[i] = o;
        return;
    }

    // ---- pack path: W1a/W1b (128x128) and W2a (128x40->48) into fp16 MFMA B-frags; W2b pairs ----
    int bid = cb - NBLK_CVT;
    if (bid < 16) {
        const float* W = (bid < 8) ? W1a : W1b;
        _Float16* P = (bid < 8) ? Pa : Pb;
        int tt = (bid & 7) * 256 + t;           // 0..2047
        int l = tt & 63, nt = (tt >> 6) & 7, kt = tt >> 9;
        int n = nt * 16 + (l & 15);
        int kb = kt * 32 + (l >> 4) * 8;
        #pragma unroll
        for (int j = 0; j < 8; ++j)
            P[(size_t)tt * 8 + j] = (_Float16)W[(size_t)(kb + j) * DIM + n];
    } else if (bid < 19) {
        int tt = (bid - 16) * 256 + t;          // 0..767
        if (tt < 768) {
            int l = tt & 63, u = tt >> 6;        // u = kt*3 + nt
            int nt = u % 3, kt = u / 3;
            int n = nt * 16 + (l & 15);
            int kb = kt * 32 + (l >> 4) * 8;
            #pragma unroll
            for (int j = 0; j < 8; ++j) {
                float wv = (n < NC) ? W2a[(size_t)(kb + j) * NC + n] : 0.f;
                Pc[(size_t)tt * 8 + j] = (_Float16)wv;
            }
        }
    } else {
        // Wq[q*NC + l] = {W2b[4q+0][l], W2b[4q+1][l], W2b[4q+2][l], W2b[4q+3][l]}  (exact f32 copy)
        for (int u = t; u < 10 * NC; u += 256) {
            int q = u / NC, c = u - q * NC;
            float4 wv;
            wv.x = W2b[(4 * q + 0) * NC + c];
            wv.y = W2b[(4 * q + 1) * NC + c];
            wv.z = W2b[(4 * q + 2) * NC + c];
            wv.w = W2b[(4 * q + 3) * NC + c];
            Wq[u] = wv;
        }
    }
}

// ---------------- layer 1 aggregation: hp = x + segsum(x[src]) ----------------
// Four rows per VMEM instruction: 16-lane group g (16 x uint4 = 256 B) loads row s[g].
// Dual-buffer software pipeline: batch k+1's csr+row loads issue before batch k is consumed.
__global__ __launch_bounds__(256) void k_gather1(const __half* __restrict__ xh, const int* __restrict__ rs,
                                                 const int* __restrict__ dg, const int* __restrict__ csr_src,
                                                 __half* __restrict__ hp) {
    int l = threadIdx.x & 63, wid = threadIdx.x >> 6;
    int n = __builtin_amdgcn_readfirstlane(blockIdx.x * 4 + wid);
    int grp = l >> 4, q = l & 15;
    const uint4* x4 = (const uint4*)xh;            // row stride: 16 uint4

    // self row issued early (lanes 0..15; consumed after the loop)
    uint4 sv;
    if (grp == 0) sv = x4[(size_t)n * 16 + q];

    float acc[8] = {0.f, 0.f, 0.f, 0.f, 0.f, 0.f, 0.f, 0.f};
    int i0 = rs[n], e = i0 + dg[n];
    int niter = (e - i0 + 7) >> 3;
    uint4 cur[2];
    if (niter > 0) {
        #pragma unroll
        for (int u = 0; u < 2; ++u) {
            int idx = i0 + u * 4 + grp;
            int s = (idx < e) ? csr_src[idx] : N_NODES;   // N_NODES = zero row (L1-hot)
            cur[u] = x4[(size_t)s * 16 + q];
        }
    }
    for (int k = 1; k < niter; ++k) {
        int base = i0 + k * 8;
        uint4 nxt[2];
        #pragma unroll
        for (int u = 0; u < 2; ++u) {
            int idx = base + u * 4 + grp;
            int s = (idx < e) ? csr_src[idx] : N_NODES;
            nxt[u] = x4[(size_t)s * 16 + q];              // issued before cur is consumed
        }
        acc_row8(acc, cur[0]); cur[0] = nxt[0];
        acc_row8(acc, cur[1]); cur[1] = nxt[1];
    }
    if (niter > 0) {
        acc_row8(acc, cur[0]);
        acc_row8(acc, cur[1]);
    }
    // combine the 4 groups (lanes l, l^16, l^32, l^48 hold the same 8 dims)
    #pragma unroll
    for (int k2 = 0; k2 < 8; ++k2) {
        acc[k2] += __shfl_xor(acc[k2], 16);
        acc[k2] += __shfl_xor(acc[k2], 32);
    }

    if (grp == 0) {
        acc_row8(acc, sv);   // add self row
        __half2 o0 = __float22half2_rn(make_float2(acc[0], acc[1]));
        __half2 o1 = __float22half2_rn(make_float2(acc[2], acc[3]));
        __half2 o2 = __float22half2_rn(make_float2(acc[4], acc[5]));
        __half2 o3 = __float22half2_rn(make_float2(acc[6], acc[7]));
        uint4 ov;
        ov.x = *(unsigned*)&o0; ov.y = *(unsigned*)&o1;
        ov.z = *(unsigned*)&o2; ov.w = *(unsigned*)&o3;
        ((uint4*)hp)[(size_t)n * 16 + q] = ov;
    }
}

// ---------------- fused MLP via fp16 MFMA: y = relu(relu(hp@W1a+b1a)@W1b+b1b) @ W2a ----------------
// Column-split waves: wave w owns col-tiles {2w,2w+1} for ALL 4 row-tiles (GEMM1/2).
// B-frags load ONCE per wave into registers; A-frags re-read from LDS per row-tile.
// GEMM3: 12 tile-tasks round-robined on 4 waves.
__global__ __launch_bounds__(256) void k_mlp(const __half* __restrict__ hp,
    const _Float16* __restrict__ Pa, const _Float16* __restrict__ Pb, const _Float16* __restrict__ Pc,
    const float* __restrict__ b1a, const float* __restrict__ b1b, __half* __restrict__ y) {
    __shared__ _Float16 A[64][136];   // +8 pad (16B): aligned frag reads
    __shared__ _Float16 H[64][136];
    int t = threadIdx.x;
    size_t row0 = (size_t)blockIdx.x * 64;

    for (int i = t; i < 1024; i += 256) {
        int r = i >> 4, c = i & 15;
        size_t g = row0 + r;
        if (g >= N_NODES) g = N_NODES - 1;    // clamped read; stores guarded below
        uint4 v = ((const uint4*)(hp + g * DIM))[c];
        *(uint4*)&A[r][c * 8] = v;
    }
    __syncthreads();

    int w = t >> 6, l = t & 63;
    int lrow = l & 15;                 // A-frag row within tile
    int kq = (l >> 4) * 8;
    int csub = (l >> 4) * 4;           // C-layout row sub-base
    int ccol = l & 15;
    int nt0 = 2 * w, nt1 = 2 * w + 1;

    // ---- GEMM1: A @ W1a + b1a, relu -> H  (wave w: cols [32w, 32w+32)) ----
    {
        f16x8 bf0[4], bf1[4];
        #pragma unroll
        for (int kt = 0; kt < 4; ++kt) {
            bf0[kt] = *(const f16x8*)(Pa + ((size_t)((kt << 3) + nt0) * 64 + l) * 8);
            bf1[kt] = *(const f16x8*)(Pa + ((size_t)((kt << 3) + nt1) * 64 + l) * 8);
        }
        float b0 = b1a[nt0 * 16 + ccol], b1 = b1a[nt1 * 16 + ccol];
        #pragma unroll
        for (int rt = 0; rt < 4; ++rt) {
            f16x8 af[4];
            #pragma unroll
            for (int kt = 0; kt < 4; ++kt) af[kt] = *(const f16x8*)&A[rt * 16 + lrow][kt * 32 + kq];
            f32x4 a0 = (f32x4){b0, b0, b0, b0}, a1 = (f32x4){b1, b1, b1, b1};
            #pragma unroll
            for (int kt = 0; kt < 4; ++kt) {
                a0 = __builtin_amdgcn_mfma_f32_16x16x32_f16(af[kt], bf0[kt], a0, 0, 0, 0);
                a1 = __builtin_amdgcn_mfma_f32_16x16x32_f16(af[kt], bf1[kt], a1, 0, 0, 0);
            }
            #pragma unroll
            for (int r = 0; r < 4; ++r) {
                H[rt * 16 + csub + r][nt0 * 16 + ccol] = (_Float16)fmaxf(a0[r], 0.f);
                H[rt * 16 + csub + r][nt1 * 16 + ccol] = (_Float16)fmaxf(a1[r], 0.f);
            }
        }
    }
    __syncthreads();

    // ---- GEMM2: H @ W1b + b1b, relu -> A ----
    {
        f16x8 bf0[4], bf1[4];
        #pragma unroll
        for (int kt = 0; kt < 4; ++kt) {
            bf0[kt] = *(const f16x8*)(Pb + ((size_t)((kt << 3) + nt0) * 64 + l) * 8);
            bf1[kt] = *(const f16x8*)(Pb + ((size_t)((kt << 3) + nt1) * 64 + l) * 8);
        }
        float b0 = b1b[nt0 * 16 + ccol], b1 = b1b[nt1 * 16 + ccol];
        #pragma unroll
        for (int rt = 0; rt < 4; ++rt) {
            f16x8 af[4];
            #pragma unroll
            for (int kt = 0; kt < 4; ++kt) af[kt] = *(const f16x8*)&H[rt * 16 + lrow][kt * 32 + kq];
            f32x4 a0 = (f32x4){b0, b0, b0, b0}, a1 = (f32x4){b1, b1, b1, b1};
            #pragma unroll
            for (int kt = 0; kt < 4; ++kt) {
                a0 = __builtin_amdgcn_mfma_f32_16x16x32_f16(af[kt], bf0[kt], a0, 0, 0, 0);
                a1 = __builtin_amdgcn_mfma_f32_16x16x32_f16(af[kt], bf1[kt], a1, 0, 0, 0);
            }
            #pragma unroll
            for (int r = 0; r < 4; ++r) {
                A[rt * 16 + csub + r][nt0 * 16 + ccol] = (_Float16)fmaxf(a0[r], 0.f);
                A[rt * 16 + csub + r][nt1 * 16 + ccol] = (_Float16)fmaxf(a1[r], 0.f);
            }
        }
    }
    __syncthreads();

    // ---- GEMM3: x2 @ W2a (bias deferred past aggregation) -> y fp16 ----
    // 12 tile-tasks (3 col-tiles x 4 row-tiles) over 4 waves, 3 tasks each (no idle wave)
    #pragma unroll
    for (int it = 0; it < 3; ++it) {
        int tt = w + 4 * it;           // 0..11
        int nt = tt % 3, rt = tt / 3;
        f16x8 bf[4], af[4];
        #pragma unroll
        for (int kt = 0; kt < 4; ++kt) {
            bf[kt] = *(const f16x8*)(Pc + ((size_t)(kt * 3 + nt) * 64 + l) * 8);
            af[kt] = *(const f16x8*)&A[rt * 16 + lrow][kt * 32 + kq];
        }
        f32x4 ya = (f32x4){0.f, 0.f, 0.f, 0.f};
        #pragma unroll
        for (int kt = 0; kt < 4; ++kt)
            ya = __builtin_amdgcn_mfma_f32_16x16x32_f16(af[kt], bf[kt], ya, 0, 0, 0);
        int col = nt * 16 + ccol;
        if (col < NC) {
            #pragma unroll
            for (int r = 0; r < 4; ++r) {
                size_t gr = row0 + rt * 16 + csub + r;
                if (gr < N_NODES) y[gr * NC + col] = __float2half(ya[r]);
            }
        }
    }
}

// ---------------- z = y + segsum(y[src]); h2 = relu(z+b2a); out = softmax(h2@W2b+b2b) ----------------
// 10-lane x 8B row groups (6 groups): accumulator state halves (4 regs) so the cross-group
// reduction tree is 12 shfl + 12 add (vs 32+40 with 5-lane x 16B groups) -- ~60 fewer VALU
// instrs/node on the bottleneck pipe. 24-edge 4-deep prologue: deg<=24 skips the loop entirely.
__global__ __launch_bounds__(256) void k_gather2(const __half* __restrict__ y, const int* __restrict__ rs,
                                                 const int* __restrict__ dg, const int* __restrict__ csr_src,
                                                 const float* __restrict__ b2a, const float4* __restrict__ Wq,
                                                 const float* __restrict__ b2b, float* __restrict__ out) {
    __shared__ float h2s[4][NC];
    int l = threadIdx.x & 63, wid = threadIdx.x >> 6;
    int n = __builtin_amdgcn_readfirstlane(blockIdx.x * 4 + wid);
    int g = l / 10, j = l - g * 10;          // g in 0..6 (lanes 60..63: g==6 -> zero row)
    const uint2* y2 = (const uint2*)y;       // row stride: 10 uint2 (80 B)

    float acc[4] = {0.f, 0.f, 0.f, 0.f};
    // self row via group 0 (issued first; independent of the loop chain)
    uint2 self;
    if (l < 10) self = y2[(size_t)n * 10 + j];

    int i0 = rs[n], d = dg[n];
    int e = i0 + d;
    // prologue: four 6-edge batches issued back-to-back (invalid lanes -> zero row, L1-hot)
    uint2 c0, c1, c2, c3;
    {
        int iA = i0 + g;
        int sA = (g < 6 && iA < e) ? csr_src[iA] : N_NODES;
        c0 = y2[(size_t)sA * 10 + j];
        int iB = i0 + 6 + g;
        int sB = (g < 6 && iB < e) ? csr_src[iB] : N_NODES;
        c1 = y2[(size_t)sB * 10 + j];
        int iC = i0 + 12 + g;
        int sC = (g < 6 && iC < e) ? csr_src[iC] : N_NODES;
        c2 = y2[(size_t)sC * 10 + j];
        int iD = i0 + 18 + g;
        int sD = (g < 6 && iD < e) ? csr_src[iD] : N_NODES;
        c3 = y2[(size_t)sD * 10 + j];
    }
    int niter = (d + 23) / 24;               // 0 if isolated node
    for (int k = 1; k < niter; ++k) {        // rare: deg > 24 (~2% of nodes)
        int base = i0 + k * 24;
        int iA = base + g;
        int sA = (g < 6 && iA < e) ? csr_src[iA] : N_NODES;
        uint2 n0 = y2[(size_t)sA * 10 + j];
        int iB = base + 6 + g;
        int sB = (g < 6 && iB < e) ? csr_src[iB] : N_NODES;
        uint2 n1 = y2[(size_t)sB * 10 + j];
        int iC = base + 12 + g;
        int sC = (g < 6 && iC < e) ? csr_src[iC] : N_NODES;
        uint2 n2 = y2[(size_t)sC * 10 + j];
        int iD = base + 18 + g;
        int sD = (g < 6 && iD < e) ? csr_src[iD] : N_NODES;
        uint2 n3 = y2[(size_t)sD * 10 + j];  // issued before c0..c3 consumed
        acc_row4(acc, c0); c0 = n0;
        acc_row4(acc, c1); c1 = n1;
        acc_row4(acc, c2); c2 = n2;
        acc_row4(acc, c3); c3 = n3;
    }
    if (d > 0) {
        acc_row4(acc, c0);
        acc_row4(acc, c1);
        acc_row4(acc, c2);
        acc_row4(acc, c3);
    }
    if (l < 10) acc_row4(acc, self);

    // cross-group reduce over g=0..5 (lanes g*10+j hold dims [4j,4j+4))
    #pragma unroll
    for (int k = 0; k < 4; ++k) acc[k] += __shfl_down(acc[k], 30);                        // g += 3
    #pragma unroll
    for (int k = 0; k < 4; ++k) acc[k] += __shfl_down(acc[k], 10) + __shfl_down(acc[k], 20); // + g1,g2

    if (l < 10) {
        float4 bb = *(const float4*)(b2a + 4 * j);
        float4 hv;
        hv.x = fmaxf(acc[0] + bb.x, 0.f);
        hv.y = fmaxf(acc[1] + bb.y, 0.f);
        hv.z = fmaxf(acc[2] + bb.z, 0.f);
        hv.w = fmaxf(acc[3] + bb.w, 0.f);
        *(float4*)&h2s[wid][4 * j] = hv;
    }
    __threadfence_block();   // same-wave LDS RAW only (each wave owns h2s[wid])

    float logit = -__builtin_inff();
    if (l < NC) {
        float4 a4 = {0.f, 0.f, 0.f, 0.f};
        #pragma unroll
        for (int q = 0; q < 10; ++q) {
            float4 h4 = *(const float4*)&h2s[wid][4 * q];   // LDS broadcast (same addr, all lanes)
            float4 w4 = Wq[q * NC + l];                     // coalesced dwordx4, L1-hot
            a4.x = fmaf(h4.x, w4.x, a4.x);
            a4.y = fmaf(h4.y, w4.y, a4.y);
            a4.z = fmaf(h4.z, w4.z, a4.z);
            a4.w = fmaf(h4.w, w4.w, a4.w);
        }
        logit = (a4.x + a4.y) + (a4.z + a4.w) + b2b[l];
    }
    float m = logit;
    #pragma unroll
    for (int d2 = 32; d2 >= 1; d2 >>= 1) m = fmaxf(m, __shfl_xor(m, d2, 64));
    float ev = (l < NC) ? __expf(logit - m) : 0.f;
    float s = ev;
    #pragma unroll
    for (int d2 = 32; d2 >= 1; d2 >>= 1) s += __shfl_xor(s, d2, 64);
    if (l < NC) out[(size_t)n * NC + l] = ev / s;
}

extern "C" void kernel_launch(void* const* d_in, const int* in_sizes, int n_in,
                              void* d_out, int out_size, void* d_ws, size_t ws_size,
                              hipStream_t stream) {
    const float* x   = (const float*)d_in[0];
    const int2*  ei  = (const int2*)d_in[1];
    const float* W1a = (const float*)d_in[2];
    const float* b1a = (const float*)d_in[3];
    const float* W1b = (const float*)d_in[4];
    const float* b1b = (const float*)d_in[5];
    const float* W2a = (const float*)d_in[6];
    const float* b2a = (const float*)d_in[7];
    const float* W2b = (const float*)d_in[8];
    const float* b2b = (const float*)d_in[9];
    float* out = (float*)d_out;

    char* w = (char*)d_ws;
    int*    dg     = (int*)(w + 0);             // 100000 ints (degree; written by k_mid/csr_local)
    int*    cnt    = (int*)(w + 400000);        // 782 ints (segment cursors, memset 0)
    int*    rs     = (int*)(w + 403200);        // 100000 ints (node csr base, segment space)
    int*    csr    = (int*)(w + 803200);        // 782*3072 ints = 9.6MB (padded segment CSR)
    __half* xh     = (__half*)(w + 10412416);   // (100000+1)x128 fp16 (incl. zero row)
    __half* hp     = (__half*)(w + 36012672);   // 100000x128 fp16 (agg result)
    __half* y      = (__half*)(w + 61612672);   // (100000+1)x40 fp16 (incl. zero row)
    _Float16* Pa   = (_Float16*)(w + 69612800); // 32KB W1a frags
    _Float16* Pb   = (_Float16*)(w + 69645568); // 32KB W1b frags
    _Float16* Pc   = (_Float16*)(w + 69678336); // 12KB W2a frags (padded to 48 cols)
    float4*   Wq   = (float4*)(w + 69690624);   // 6.4KB W2b paired (10 x 40 float4)
    int*    seg    = (int*)hp;                  // 9.6MB segments OVERLAY hp (dead until gather1)
    // total ws needed: 69,697,024 bytes

    (void)hipMemsetAsync(w + 400000, 0, 3200, stream);  // zero cnt only
    k_binfill  <<<NBLK_FILL, 256, 0, stream>>>(ei, cnt, seg);
    k_mid      <<<NBUCKET + NBLK_CVT + NBLK_PACK, 256, 0, stream>>>(dg, cnt, seg, rs, csr,
                                                                    x, xh, y, W1a, W1b, W2a, W2b,
                                                                    Pa, Pb, Pc, Wq);
    k_gather1  <<<N_NODES / 4, 256, 0, stream>>>(xh, rs, dg, csr, hp);
    k_mlp      <<<(N_NODES + 63) / 64, 256, 0, stream>>>(hp, Pa, Pb, Pc, b1a, b1b, y);
    k_gather2  <<<N_NODES / 4, 256, 0, stream>>>(y, rs, dg, csr, b2a, Wq, b2b, out);
}